// Round 5
// baseline (117.615 us; speedup 1.0000x reference)
//
#include <hip/hip_runtime.h>

#define NMODELS 128
#define SZ_IN 256
#define SZ_OUT 256
#define CHUNK 16
#define MAXCHUNKS 384  // upper bound on sum(ceil(cnt_m/16)) = 128 + 4096/16

typedef __attribute__((ext_vector_type(4))) float f32x4;
typedef __attribute__((ext_vector_type(2))) float f32x2;

// Workspace layout (ints):
//   off[0..128] | sorted[0..B) | cm[384] | cs0[384] | ccnt[384] | nc
// Offsets chosen below in kernel_launch.

// Prep: single block. LDS histogram -> serial prefix (128) -> scatter +
// chunk descriptors (model id, start in sorted[], sample count per chunk).
// Scatter order is atomic-nondeterministic but globally consistent within a
// run; per-sample math (full K, sequential) is order-independent -> exact.
__global__ __launch_bounds__(256) void prep_v5(const int* __restrict__ ids, int B,
                                               int* __restrict__ off,
                                               int* __restrict__ sorted,
                                               int* __restrict__ cm,
                                               int* __restrict__ cs0,
                                               int* __restrict__ ccnt,
                                               int* __restrict__ ncp) {
  __shared__ int cnt[NMODELS];
  __shared__ int pos[NMODELS];
  __shared__ int coff[NMODELS];
  const int t = threadIdx.x;
  if (t < NMODELS) cnt[t] = 0;
  __syncthreads();
  for (int b = t; b < B; b += 256) atomicAdd(&cnt[ids[b]], 1);
  __syncthreads();
  if (t == 0) {
    int run = 0, crun = 0;
    for (int m = 0; m < NMODELS; ++m) {
      pos[m] = run;
      off[m] = run;
      coff[m] = crun;
      crun += (cnt[m] + CHUNK - 1) / CHUNK;
      run += cnt[m];
    }
    off[NMODELS] = run;
    *ncp = crun;
  }
  __syncthreads();
  if (t < NMODELS) {
    const int n = cnt[t], base = off[t], cb = coff[t];
    for (int c = 0; c * CHUNK < n; ++c) {
      cm[cb + c] = t;
      cs0[cb + c] = base + c * CHUNK;
      const int rem = n - c * CHUNK;
      ccnt[cb + c] = rem < CHUNK ? rem : CHUNK;
    }
  }
  for (int b = t; b < B; b += 256) {
    const int p = atomicAdd(&pos[ids[b]], 1);
    sorted[p] = b;
  }
}

// Main: blockIdx.x = chunk_slot*2 + coltile. 256 threads = 4 waves.
// Thread owns 2 cols (coalesced f32x2) x 4 samples (wave-uniform group),
// full K=256 (exact fp32, sequential i order). A[16][256] staged in LDS,
// read as wave-uniform broadcasts (conflict-free). acc = 8 VGPRs.
__global__ __launch_bounds__(256) void linmulti_v5(
    const float* __restrict__ inp, const float* __restrict__ wlut,
    const float* __restrict__ blut, const int* __restrict__ sorted,
    const int* __restrict__ cm, const int* __restrict__ cs0,
    const int* __restrict__ ccnt, const int* __restrict__ ncp,
    float* __restrict__ out) {
  const int cj = blockIdx.x >> 1;
  if (cj >= *ncp) return;
  const int ct = blockIdx.x & 1;
  const int m = cm[cj];
  const int s0 = cs0[cj];
  const int scnt = ccnt[cj];
  const int tid = threadIdx.x;

  __shared__ float As[CHUNK * SZ_IN];  // 16 KB
  __shared__ int sidx[CHUNK];

  if (tid < CHUNK) {
    const int p = (tid < scnt) ? tid : (scnt - 1);  // clamp pad slots
    sidx[tid] = sorted[s0 + p];
  }
  __syncthreads();
#pragma unroll
  for (int v = 0; v < 4; ++v) {
    const int e4 = v * 256 + tid;  // [0,1024) float4s
    const int s = e4 >> 6, f4 = e4 & 63;
    ((f32x4*)As)[e4] = ((const f32x4*)(inp + (size_t)sidx[s] * SZ_IN))[f4];
  }
  __syncthreads();

  const int c2 = ct * 128 + (tid & 63) * 2;  // this thread's 2 cols
  const int sg = (tid >> 6) * 4;             // wave-uniform sample group
  const float* __restrict__ Wc = wlut + (size_t)m * (SZ_IN * SZ_OUT) + c2;
  const f32x2 bias2 = *(const f32x2*)(blut + m * SZ_OUT + c2);

  f32x2 acc[4];
#pragma unroll
  for (int s = 0; s < 4; ++s) acc[s] = (f32x2){0.f, 0.f};

#pragma unroll 2
  for (int i0 = 0; i0 < SZ_IN; i0 += 8) {
    f32x2 w[8];
#pragma unroll
    for (int j = 0; j < 8; ++j)
      w[j] = *(const f32x2*)(Wc + (size_t)(i0 + j) * SZ_OUT);
#pragma unroll
    for (int s = 0; s < 4; ++s) {
      const float* ar = As + (sg + s) * SZ_IN + i0;
      const f32x4 a0 = *(const f32x4*)ar;        // broadcast ds_read_b128
      const f32x4 a1 = *(const f32x4*)(ar + 4);  // conflict-free
#pragma unroll
      for (int j = 0; j < 4; ++j) {
        acc[s][0] = fmaf(a0[j], w[j][0], acc[s][0]);
        acc[s][1] = fmaf(a0[j], w[j][1], acc[s][1]);
      }
#pragma unroll
      for (int j = 0; j < 4; ++j) {
        acc[s][0] = fmaf(a1[j], w[4 + j][0], acc[s][0]);
        acc[s][1] = fmaf(a1[j], w[4 + j][1], acc[s][1]);
      }
    }
  }

#pragma unroll
  for (int s = 0; s < 4; ++s) {
    if (sg + s < scnt) {
      f32x2 r;
      r[0] = acc[s][0] + bias2[0];
      r[1] = acc[s][1] + bias2[1];
      *(f32x2*)(out + (size_t)sidx[sg + s] * SZ_OUT + c2) = r;
    }
  }
}

extern "C" void kernel_launch(void* const* d_in, const int* in_sizes, int n_in,
                              void* d_out, int out_size, void* d_ws, size_t ws_size,
                              hipStream_t stream) {
  const float* inp = (const float*)d_in[0];
  const int* ids = (const int*)d_in[1];
  const float* wlut = (const float*)d_in[2];
  const float* blut = (const float*)d_in[3];
  float* out = (float*)d_out;
  const int B = in_sizes[1];

  int* w = (int*)d_ws;
  int* off = w;            // 129 (padded to 160)
  int* sorted = w + 160;   // B
  int* cm = w + 160 + 4096;
  int* cs0 = cm + MAXCHUNKS;
  int* ccnt = cs0 + MAXCHUNKS;
  int* ncp = ccnt + MAXCHUNKS;

  prep_v5<<<1, 256, 0, stream>>>(ids, B, off, sorted, cm, cs0, ccnt, ncp);
  linmulti_v5<<<2 * MAXCHUNKS, 256, 0, stream>>>(inp, wlut, blut, sorted, cm,
                                                 cs0, ccnt, ncp, out);
}

// Round 6
// 108.398 us; speedup vs baseline: 1.0850x; 1.0850x over previous
//
#include <hip/hip_runtime.h>

#define NMODELS 128
#define SZ_IN 256
#define SZ_OUT 256
#define CHUNK 16
#define MAXCHUNKS 384  // >= sum(ceil(cnt_m/16)) worst case (128 + 4096/16)
#define NT 512         // 8 waves: 2 K-halves x 4 sample-groups

typedef __attribute__((ext_vector_type(4))) float f32x4;
typedef __attribute__((ext_vector_type(2))) float f32x2;

// ---------- Prep: 1 block, fully parallel (no serial-128 chain) ----------
// Histogram via LDS atomics (vectorized int4 id loads), packed Hillis-Steele
// scan for sample-offsets AND chunk-offsets in one pass, parallel descriptor
// write, parallel scatter. Scatter order is atomic-nondeterministic but all
// consumers share the one global sorted[] and per-sample math is full-K
// sequential -> exact regardless of order.
__global__ __launch_bounds__(256) void prep_v6(const int* __restrict__ ids, int B,
                                               int* __restrict__ sorted,
                                               int* __restrict__ cm,
                                               int* __restrict__ cs0,
                                               int* __restrict__ ccnt,
                                               int* __restrict__ ncp) {
  __shared__ int cnt[NMODELS];
  __shared__ int scan[NMODELS];
  __shared__ int pos[NMODELS];
  const int t = threadIdx.x;
  if (t < NMODELS) cnt[t] = 0;
  __syncthreads();

  const int4* idv = (const int4*)ids;  // B multiple of 4 (B=4096)
  const int n4 = B >> 2;
  for (int e = t; e < n4; e += 256) {
    const int4 r = idv[e];
    atomicAdd(&cnt[r.x], 1);
    atomicAdd(&cnt[r.y], 1);
    atomicAdd(&cnt[r.z], 1);
    atomicAdd(&cnt[r.w], 1);
  }
  __syncthreads();

  // packed inclusive scan: low 16 bits = samples, high 16 = chunks
  if (t < NMODELS) {
    const int c = cnt[t];
    scan[t] = c + ((((c + CHUNK - 1) / CHUNK) & 0xFFFF) << 16);
  }
  __syncthreads();
  for (int d = 1; d < NMODELS; d <<= 1) {
    int add = 0;
    if (t < NMODELS && t >= d) add = scan[t - d];
    __syncthreads();
    if (t < NMODELS) scan[t] += add;
    __syncthreads();
  }
  if (t == 0) *ncp = scan[NMODELS - 1] >> 16;
  if (t < NMODELS) {
    const int n = cnt[t];
    const int nch = (n + CHUNK - 1) / CHUNK;
    const int off_m = (scan[t] & 0xFFFF) - n;
    const int coff_m = (scan[t] >> 16) - nch;
    pos[t] = off_m;
    for (int c = 0; c < nch; ++c) {
      cm[coff_m + c] = t;
      cs0[coff_m + c] = off_m + c * CHUNK;
      const int rem = n - c * CHUNK;
      ccnt[coff_m + c] = rem < CHUNK ? rem : CHUNK;
    }
  }
  __syncthreads();
  for (int e = t; e < n4; e += 256) {
    const int4 r = idv[e];
    const int b = e * 4;
    sorted[atomicAdd(&pos[r.x], 1)] = b;
    sorted[atomicAdd(&pos[r.y], 1)] = b + 1;
    sorted[atomicAdd(&pos[r.z], 1)] = b + 2;
    sorted[atomicAdd(&pos[r.w], 1)] = b + 3;
  }
}

// ---------- Main: blockIdx.x = chunk_slot*2 + coltile ----------
// 512 threads = 8 waves. kh = tid>>8 (K-half, 128 k's), sample group
// sg = ((tid>>6)&3)*4, thread owns 2 cols: c = (tid&63)*2 within the
// 128-col tile. acc = 4 samples x f32x2 = 8 VGPRs. Register double-buffer
// on weight loads. K-halves reduced through LDS (As reused). Pure fp32.
__global__ __launch_bounds__(NT) void linmulti_v6(
    const float* __restrict__ inp, const float* __restrict__ wlut,
    const float* __restrict__ blut, const int* __restrict__ sorted,
    const int* __restrict__ cm, const int* __restrict__ cs0,
    const int* __restrict__ ccnt, const int* __restrict__ ncp,
    float* __restrict__ out) {
  const int cj = blockIdx.x >> 1;
  if (cj >= *ncp) return;
  const int ct = blockIdx.x & 1;
  const int m = cm[cj];
  const int s0 = cs0[cj];
  const int scnt = ccnt[cj];
  const int tid = threadIdx.x;

  __shared__ float As[CHUNK * SZ_IN];  // 16 KB; head reused as reduce buf
  __shared__ int sidx[CHUNK];

  if (tid < CHUNK) {
    const int p = (tid < scnt) ? tid : (scnt - 1);  // clamp pads
    sidx[tid] = sorted[s0 + p];
  }
  __syncthreads();
#pragma unroll
  for (int v = 0; v < 2; ++v) {
    const int e4 = v * NT + tid;  // [0,1024) float4s
    const int s = e4 >> 6, f4 = e4 & 63;
    ((f32x4*)As)[e4] = ((const f32x4*)(inp + (size_t)sidx[s] * SZ_IN))[f4];
  }
  __syncthreads();

  const int c = (tid & 63) * 2;          // col within 128-tile (f32x2)
  const int kh = tid >> 8;               // K-half (wave-uniform)
  const int sg = ((tid >> 6) & 3) * 4;   // sample group (wave-uniform)
  const int ibase = kh * 128;
  const int gcol = ct * 128 + c;
  const float* __restrict__ Wc =
      wlut + (size_t)m * (SZ_IN * SZ_OUT) + (size_t)ibase * SZ_OUT + gcol;

  f32x2 acc[4];
#pragma unroll
  for (int s = 0; s < 4; ++s) acc[s] = (f32x2){0.f, 0.f};

  f32x2 w0[8];
#pragma unroll
  for (int j = 0; j < 8; ++j) w0[j] = *(const f32x2*)(Wc + (size_t)j * SZ_OUT);

#pragma unroll 1
  for (int i0 = 0; i0 < 128; i0 += 8) {
    // prefetch next 8 rows (wraps to row 0 on last iter; harmless)
    const int nxt = (i0 + 8) & 127;
    f32x2 w1[8];
#pragma unroll
    for (int j = 0; j < 8; ++j)
      w1[j] = *(const f32x2*)(Wc + (size_t)(nxt + j) * SZ_OUT);

#pragma unroll
    for (int s = 0; s < 4; ++s) {
      const float* ar = As + (sg + s) * SZ_IN + ibase + i0;
      const f32x4 a0 = *(const f32x4*)ar;        // broadcast, conflict-free
      const f32x4 a1 = *(const f32x4*)(ar + 4);
#pragma unroll
      for (int j = 0; j < 4; ++j) {
        acc[s][0] = fmaf(a0[j], w0[j][0], acc[s][0]);
        acc[s][1] = fmaf(a0[j], w0[j][1], acc[s][1]);
      }
#pragma unroll
      for (int j = 0; j < 4; ++j) {
        acc[s][0] = fmaf(a1[j], w0[4 + j][0], acc[s][0]);
        acc[s][1] = fmaf(a1[j], w0[4 + j][1], acc[s][1]);
      }
    }
#pragma unroll
    for (int j = 0; j < 8; ++j) w0[j] = w1[j];
  }

  // K-half reduce through LDS head (8 KB region: 16 samples x 128 cols)
  __syncthreads();  // all FMAs (A-reads) done
  if (kh == 1) {
#pragma unroll
    for (int s = 0; s < 4; ++s)
      *(f32x2*)(As + (sg + s) * 128 + c) = acc[s];  // 2-way alias = free
  }
  __syncthreads();
  if (kh == 0) {
    const f32x2 bias2 = *(const f32x2*)(blut + m * SZ_OUT + gcol);
#pragma unroll
    for (int s = 0; s < 4; ++s) {
      if (sg + s < scnt) {
        const f32x2 oth = *(const f32x2*)(As + (sg + s) * 128 + c);
        f32x2 r;
        r[0] = acc[s][0] + oth[0] + bias2[0];
        r[1] = acc[s][1] + oth[1] + bias2[1];
        *(f32x2*)(out + (size_t)sidx[sg + s] * SZ_OUT + gcol) = r;
      }
    }
  }
}

extern "C" void kernel_launch(void* const* d_in, const int* in_sizes, int n_in,
                              void* d_out, int out_size, void* d_ws, size_t ws_size,
                              hipStream_t stream) {
  const float* inp = (const float*)d_in[0];
  const int* ids = (const int*)d_in[1];
  const float* wlut = (const float*)d_in[2];
  const float* blut = (const float*)d_in[3];
  float* out = (float*)d_out;
  const int B = in_sizes[1];

  int* w = (int*)d_ws;
  int* sorted = w;                 // B ints
  int* cm = w + 4096;              // MAXCHUNKS
  int* cs0 = cm + MAXCHUNKS;
  int* ccnt = cs0 + MAXCHUNKS;
  int* ncp = ccnt + MAXCHUNKS;

  prep_v6<<<1, 256, 0, stream>>>(ids, B, sorted, cm, cs0, ccnt, ncp);
  linmulti_v6<<<2 * MAXCHUNKS, NT, 0, stream>>>(inp, wlut, blut, sorted, cm,
                                                cs0, ccnt, ncp, out);
}